// Round 5
// baseline (230.939 us; speedup 1.0000x reference)
//
#include <hip/hip_runtime.h>
#include <hip/hip_bf16.h>

// Problem constants
#define B_SZ   64
#define L_SZ   52
#define DMODEL 4096
#define H_SZ   32
#define C_SZ   128   // NEW_C = DMODEL/H
#define DK     128   // D_K == D_V

// Output GEMM dims: (B*L) x DMODEL = 3328 x 4096, K = 4096
#define GM 3328
#define GN 4096
#define GK 4096

typedef __bf16 bf16x8 __attribute__((ext_vector_type(8)));
typedef float  f32x4  __attribute__((ext_vector_type(4)));

__device__ __forceinline__ void gload_lds16(const void* g, void* l) {
  __builtin_amdgcn_global_load_lds(
      (__attribute__((address_space(1))) void*)(void*)g,
      (__attribute__((address_space(3))) void*)l, 16, 0, 0);
}

// ---------------------------------------------------------------------------
// Kernel 1a: Wo (4096x4096 fp32 [m][n]) -> WoT (4096x4096 bf16 [n][m])
// ---------------------------------------------------------------------------
__global__ __launch_bounds__(256) void wo_transpose_kernel(
    const float* __restrict__ Wo, __hip_bfloat16* __restrict__ WoT) {
  __shared__ float tile[64][65];
  const int nt = blockIdx.x, mt = blockIdx.y;
  const int t = threadIdx.x;
  const int r  = t >> 4;
  const int c4 = (t & 15) << 2;
#pragma unroll
  for (int p = 0; p < 4; ++p) {
    const int rr = r + p * 16;
    const float4 v = *(const float4*)(Wo + (size_t)(mt * 64 + rr) * 4096 + nt * 64 + c4);
    tile[rr][c4 + 0] = v.x; tile[rr][c4 + 1] = v.y;
    tile[rr][c4 + 2] = v.z; tile[rr][c4 + 3] = v.w;
  }
  __syncthreads();
#pragma unroll
  for (int p = 0; p < 4; ++p) {
    const int rr = r + p * 16;
    union { __hip_bfloat16 h[4]; ushort4 u; } o4;
#pragma unroll
    for (int e = 0; e < 4; ++e) o4.h[e] = __float2bfloat16(tile[c4 + e][rr]);
    *(ushort4*)(WoT + (size_t)(nt * 64 + rr) * 4096 + mt * 64 + c4) = o4.u;
  }
}

// ---------------------------------------------------------------------------
// Kernel 1b: Wq/Wk/Wv [h][c][k] fp32 -> [h][k][c] bf16   (batched 128x128 T)
// ---------------------------------------------------------------------------
__global__ __launch_bounds__(256) void w3_transpose_kernel(
    const float* __restrict__ Wq, const float* __restrict__ Wk,
    const float* __restrict__ Wv, __hip_bfloat16* __restrict__ WqT,
    __hip_bfloat16* __restrict__ WkT, __hip_bfloat16* __restrict__ WvT) {
  __shared__ float tile[64][65];
  const int bz = blockIdx.z;
  const float* in = (bz < 32 ? Wq : (bz < 64 ? Wk : Wv)) + (size_t)(bz & 31) * 16384;
  __hip_bfloat16* out = (bz < 32 ? WqT : (bz < 64 ? WkT : WvT)) + (size_t)(bz & 31) * 16384;
  const int nt = blockIdx.x, mt = blockIdx.y;  // 0..1
  const int t = threadIdx.x;
  const int r  = t >> 4;
  const int c4 = (t & 15) << 2;
#pragma unroll
  for (int p = 0; p < 4; ++p) {
    const int rr = r + p * 16;
    const float4 v = *(const float4*)(in + (size_t)(mt * 64 + rr) * 128 + nt * 64 + c4);
    tile[rr][c4 + 0] = v.x; tile[rr][c4 + 1] = v.y;
    tile[rr][c4 + 2] = v.z; tile[rr][c4 + 3] = v.w;
  }
  __syncthreads();
#pragma unroll
  for (int p = 0; p < 4; ++p) {
    const int rr = r + p * 16;
    union { __hip_bfloat16 h[4]; ushort4 u; } o4;
#pragma unroll
    for (int e = 0; e < 4; ++e) o4.h[e] = __float2bfloat16(tile[c4 + e][rr]);
    *(ushort4*)(out + (size_t)(nt * 64 + rr) * 128 + mt * 64 + c4) = o4.u;
  }
}

// ---------------------------------------------------------------------------
// Kernel 2: per-(b,h) MFMA attention. 256 threads = 4 waves. (unchanged)
// ---------------------------------------------------------------------------
template <bool TRANSPOSED>
__device__ __forceinline__ void wave_proj(
    const __hip_bfloat16* __restrict__ xs, const __hip_bfloat16* __restrict__ WT,
    const float* __restrict__ bias, __hip_bfloat16* __restrict__ out,
    int n0, int r16, int kq) {
  f32x4 acc[4][2] = {};
  bf16x8 bfrag[2][4];
#pragma unroll
  for (int nt = 0; nt < 2; ++nt)
#pragma unroll
    for (int kk = 0; kk < 4; ++kk)
      bfrag[nt][kk] = *(const bf16x8*)(WT + (n0 + nt * 16 + r16) * 128 + kk * 32 + kq * 8);
#pragma unroll
  for (int kk = 0; kk < 4; ++kk) {
    bf16x8 a[4];
#pragma unroll
    for (int mt = 0; mt < 4; ++mt)
      a[mt] = *(const bf16x8*)(xs + (mt * 16 + r16) * 136 + kk * 32 + kq * 8);
#pragma unroll
    for (int mt = 0; mt < 4; ++mt)
#pragma unroll
      for (int nt = 0; nt < 2; ++nt)
        acc[mt][nt] = __builtin_amdgcn_mfma_f32_16x16x32_bf16(a[mt], bfrag[nt][kk], acc[mt][nt], 0, 0, 0);
  }
#pragma unroll
  for (int nt = 0; nt < 2; ++nt) {
    const int col = n0 + nt * 16 + r16;
    const float bv = bias[col];
#pragma unroll
    for (int mt = 0; mt < 4; ++mt) {
      const int m0 = mt * 16 + kq * 4;
      if (!TRANSPOSED) {
#pragma unroll
        for (int i = 0; i < 4; ++i)
          out[(m0 + i) * 136 + col] = __float2bfloat16(acc[mt][nt][i] + bv);
      } else {
        union { __hip_bfloat16 h[4]; ushort4 u; } o4;
        if (m0 < 52) {
#pragma unroll
          for (int i = 0; i < 4; ++i) o4.h[i] = __float2bfloat16(acc[mt][nt][i] + bv);
        } else {
          o4.u = make_ushort4(0, 0, 0, 0);   // pad keys: v rows 52..63 = 0
        }
        *(ushort4*)(out + col * 72 + m0) = o4.u;
      }
    }
  }
}

__global__ __launch_bounds__(256, 2) void attn_kernel(
    const float* __restrict__ Qin, const float* __restrict__ Kin,
    const float* __restrict__ Vin,
    const __hip_bfloat16* __restrict__ WqT, const float* __restrict__ bq,
    const __hip_bfloat16* __restrict__ WkT, const float* __restrict__ bk,
    const __hip_bfloat16* __restrict__ WvT, const float* __restrict__ bv,
    __hip_bfloat16* __restrict__ Oc) {
  __shared__ __align__(16) char lds[70656];
  __hip_bfloat16* xs0  = (__hip_bfloat16*)(lds);
  __hip_bfloat16* xs1  = (__hip_bfloat16*)(lds + 17408);
  __hip_bfloat16* xs2  = (__hip_bfloat16*)(lds + 34816);
  __hip_bfloat16* vT   = (__hip_bfloat16*)(lds + 52224);
  __hip_bfloat16* q_sh = (__hip_bfloat16*)(lds + 34816);
  __hip_bfloat16* k_sh = (__hip_bfloat16*)(lds);
  float*          s_sh = (float*)(lds + 17408);
  __hip_bfloat16* p_sh = (__hip_bfloat16*)(lds + 34816);

  const int h = blockIdx.x, bb = blockIdx.y;
  const int t = threadIdx.x;
  const int w = t >> 6, lane = t & 63;
  const int r16 = lane & 15, kq = lane >> 4;
  const size_t xoff = (size_t)bb * (L_SZ * DMODEL) + (size_t)h * (L_SZ * C_SZ);

  {
    const float* xp[3] = {Qin + xoff, Kin + xoff, Vin + xoff};
    __hip_bfloat16* xd[3] = {xs0, xs1, xs2};
#pragma unroll
    for (int tz = 0; tz < 3; ++tz) {
      const float* X = xp[tz];
      __hip_bfloat16* xs = xd[tz];
      for (int idx = t; idx < 52 * 32; idx += 256) {
        const int row = idx >> 5, c4 = (idx & 31) << 2;
        const float4 v = *(const float4*)(X + row * 128 + c4);
        union { __hip_bfloat16 h[4]; ushort4 u; } o4;
        o4.h[0] = __float2bfloat16(v.x); o4.h[1] = __float2bfloat16(v.y);
        o4.h[2] = __float2bfloat16(v.z); o4.h[3] = __float2bfloat16(v.w);
        *(ushort4*)(xs + row * 136 + c4) = o4.u;
      }
      if (t < 12 * 17) {
        const int row = 52 + t / 17, c8 = (t % 17) * 8;
        *(uint4*)(xs + row * 136 + c8) = make_uint4(0, 0, 0, 0);
      }
    }
  }
  __syncthreads();

  wave_proj<true>(xs2, WvT + (size_t)h * 16384, bv + h * 128, vT, w * 32, r16, kq);
  __syncthreads();
  wave_proj<false>(xs0, WqT + (size_t)h * 16384, bq + h * 128, q_sh, w * 32, r16, kq);
  __syncthreads();
  wave_proj<false>(xs1, WkT + (size_t)h * 16384, bk + h * 128, k_sh, w * 32, r16, kq);
  __syncthreads();

  {
    const int n0 = w * 16;
    f32x4 sacc[4] = {};
#pragma unroll
    for (int kk = 0; kk < 4; ++kk) {
      const bf16x8 bf_ = *(const bf16x8*)(k_sh + (n0 + r16) * 136 + kk * 32 + kq * 8);
#pragma unroll
      for (int mt = 0; mt < 4; ++mt) {
        const bf16x8 a = *(const bf16x8*)(q_sh + (mt * 16 + r16) * 136 + kk * 32 + kq * 8);
        sacc[mt] = __builtin_amdgcn_mfma_f32_16x16x32_bf16(a, bf_, sacc[mt], 0, 0, 0);
      }
    }
    const float scale = 0.08838834764831845f;  // 1/sqrt(128)
#pragma unroll
    for (int mt = 0; mt < 4; ++mt)
#pragma unroll
      for (int i = 0; i < 4; ++i)
        s_sh[(mt * 16 + kq * 4 + i) * 68 + n0 + r16] = sacc[mt][i] * scale;
  }
  __syncthreads();

  {
    const int r = t >> 2, qd = t & 3;
    if (r < 52) {
      float v[16];
      float mx = -3e38f;
#pragma unroll
      for (int j4 = 0; j4 < 4; ++j4) {
        const f32x4 s4 = *(const f32x4*)(s_sh + r * 68 + qd * 16 + j4 * 4);
#pragma unroll
        for (int e = 0; e < 4; ++e) {
          const int col = qd * 16 + j4 * 4 + e;
          const float val = (col <= r) ? s4[e] : -3e38f;
          v[j4 * 4 + e] = val;
          mx = fmaxf(mx, val);
        }
      }
      mx = fmaxf(mx, __shfl_xor(mx, 1));
      mx = fmaxf(mx, __shfl_xor(mx, 2));
      float ex[16];
      float sum = 0.f;
#pragma unroll
      for (int j = 0; j < 16; ++j) {
        const int col = qd * 16 + j;
        const float e = (col <= r) ? __expf(v[j] - mx) : 0.f;
        ex[j] = e; sum += e;
      }
      sum += __shfl_xor(sum, 1);
      sum += __shfl_xor(sum, 2);
      const float inv = 1.0f / sum;
      union { __hip_bfloat16 h[8]; uint4 q; } p0, p1;
#pragma unroll
      for (int j = 0; j < 8; ++j) {
        p0.h[j] = __float2bfloat16(ex[j] * inv);
        p1.h[j] = __float2bfloat16(ex[8 + j] * inv);
      }
      *(uint4*)(p_sh + r * 72 + qd * 16)     = p0.q;
      *(uint4*)(p_sh + r * 72 + qd * 16 + 8) = p1.q;
    } else {
      *(uint4*)(p_sh + r * 72 + qd * 16)     = make_uint4(0, 0, 0, 0);
      *(uint4*)(p_sh + r * 72 + qd * 16 + 8) = make_uint4(0, 0, 0, 0);
    }
  }
  __syncthreads();

  {
    const int n0 = w * 32;
    f32x4 oacc[4][2] = {};
#pragma unroll
    for (int kk = 0; kk < 2; ++kk) {
      bf16x8 bfr[2];
#pragma unroll
      for (int nt = 0; nt < 2; ++nt)
        bfr[nt] = *(const bf16x8*)(vT + (n0 + nt * 16 + r16) * 72 + kk * 32 + kq * 8);
#pragma unroll
      for (int mt = 0; mt < 4; ++mt) {
        const bf16x8 a = *(const bf16x8*)(p_sh + (mt * 16 + r16) * 72 + kk * 32 + kq * 8);
#pragma unroll
        for (int nt = 0; nt < 2; ++nt)
          oacc[mt][nt] = __builtin_amdgcn_mfma_f32_16x16x32_bf16(a, bfr[nt], oacc[mt][nt], 0, 0, 0);
      }
    }
    const size_t obase = (size_t)bb * 52 * 4096 + (size_t)h * 128;
#pragma unroll
    for (int nt = 0; nt < 2; ++nt) {
      const int col = n0 + nt * 16 + r16;
#pragma unroll
      for (int mt = 0; mt < 4; ++mt) {
        const int row0 = mt * 16 + kq * 4;
#pragma unroll
        for (int i = 0; i < 4; ++i) {
          const int row = row0 + i;
          if (row < 52)
            Oc[obase + (size_t)row * 4096 + col] = __float2bfloat16(oacc[mt][nt][i]);
        }
      }
    }
  }
}

// ---------------------------------------------------------------------------
// Kernel 3: C(3328x4096) = Oc @ WoT^T + bo — 4-phase rolling-prefetch schedule
// (see header comment in the draft above; this is the corrected version)
// ---------------------------------------------------------------------------
#define STAGE(GBASE, REGOFF, KT, KS, WB) do {                                  \
    const __hip_bfloat16* s_ = (GBASE) + (size_t)(KT) * 64 + (KS) * 32;        \
    char* d_ = (WB) + (REGOFF) + ((KS) ? 16384 : 0) + t * 16;                  \
    gload_lds16(s_, d_);                                                       \
    gload_lds16(s_ + (size_t)128 * GK, d_ + 8192);                             \
  } while (0)

#define WAIT_LGKM0()                                                           \
  asm volatile("s_waitcnt lgkmcnt(0)" ::: "memory");                           \
  __builtin_amdgcn_sched_barrier(0)

#define LOAD_AF(DST, BASE)                                                     \
  _Pragma("unroll")                                                            \
  for (int mf = 0; mf < 4; ++mf)                                               \
    DST[mf] = *(const bf16x8*)((BASE) + mf * 1024)

#define LOAD_BF(DST, BASE)                                                     \
  _Pragma("unroll")                                                            \
  for (int nf = 0; nf < 4; ++nf)                                               \
    DST[nf] = *(const bf16x8*)((BASE) + nf * 1024)

#define CLUSTER(AF, BF, MQ)                                                    \
  __builtin_amdgcn_sched_barrier(0);                                           \
  __builtin_amdgcn_s_setprio(1);                                               \
  _Pragma("unroll")                                                            \
  for (int mf = 0; mf < 4; ++mf)                                               \
    _Pragma("unroll")                                                          \
    for (int nf = 0; nf < 4; ++nf)                                             \
      acc[(MQ) * 4 + mf][nf] = __builtin_amdgcn_mfma_f32_16x16x32_bf16(        \
          AF[mf], BF[nf], acc[(MQ) * 4 + mf][nf], 0, 0, 0);                    \
  __builtin_amdgcn_s_setprio(0)

__global__ __launch_bounds__(512, 2) void out_gemm_kernel(
    const __hip_bfloat16* __restrict__ A, const __hip_bfloat16* __restrict__ Bt,
    const float* __restrict__ bias, float* __restrict__ C) {
  __shared__ __align__(16) char lds[131072];   // 2 bufs x 64 KB

  int bid = blockIdx.x;
  bid = (bid & 7) * 26 + (bid >> 3);     // XCD swizzle, 208 % 8 == 0 (bijective)
  const int tm = bid >> 4;               // 0..12
  const int tn = bid & 15;               // 0..15

  const int t = threadIdx.x;
  const int w = t >> 6, lane = t & 63;
  const int wm = w >> 2, wn = w & 3;     // 2M x 4N waves; wave tile 128x64
  const int r16 = lane & 15, kq = lane >> 4;

  const int srow = t >> 2;
  const int sgslot = (t & 3) ^ ((srow >> 1) & 3);
  const __hip_bfloat16* gA0 = A  + (size_t)(tm * 256 + srow) * GK + sgslot * 8;
  const __hip_bfloat16* gB0 = Bt + (size_t)(tn * 256 + srow) * GK + sgslot * 8;

  const int slotr = kq ^ ((r16 >> 1) & 3);
  const int aB0 = (wm * 128 + r16) * 64 + slotr * 16;           // A, mq0, ks0
  const int bB  = 32768 + (wn * 64 + r16) * 64 + slotr * 16;    // B, ks0

  f32x4 acc[8][4] = {};
  bf16x8 af0[4], af1[4], bf0[4], bf1[4];

  // prologue: tile0 -> buf0, tile1 -> buf1 (8 gload instructions each)
  STAGE(gA0, 0,     0, 0, lds);
  STAGE(gA0, 0,     0, 1, lds);
  STAGE(gB0, 32768, 0, 0, lds);
  STAGE(gB0, 32768, 0, 1, lds);
  STAGE(gA0, 0,     1, 0, lds + 65536);
  STAGE(gA0, 0,     1, 1, lds + 65536);
  STAGE(gB0, 32768, 1, 0, lds + 65536);
  STAGE(gB0, 32768, 1, 1, lds + 65536);
  asm volatile("s_waitcnt vmcnt(8)" ::: "memory");   // own tile0 loads landed
  __builtin_amdgcn_s_barrier();                      // all waves' tile0 landed
  LOAD_AF(af0, lds + aB0);                           // tile0 ks0 mq0
  LOAD_BF(bf0, lds + bB);                            // tile0 ks0

#pragma unroll 1
  for (int kt = 0; kt < 64; ++kt) {
    char* rb = lds + ((kt & 1) << 16);
    char* nb = lds + (((kt + 1) & 1) << 16);

    // P0 (ks0,mq0): prefetch af(ks0,mq1); MFMA on af0/bf0
    WAIT_LGKM0();
    LOAD_AF(af1, rb + 4096 + aB0);
    CLUSTER(af0, bf0, 0);

    // P1 (ks0,mq1): prefetch af(ks1,mq0) + bf(ks1); MFMA on af1/bf0
    WAIT_LGKM0();
    LOAD_AF(af0, rb + 16384 + aB0);
    LOAD_BF(bf1, rb + 16384 + bB);
    CLUSTER(af1, bf0, 1);

    // P2 (ks1,mq0): prefetch af(ks1,mq1); MFMA on af0/bf1
    WAIT_LGKM0();
    LOAD_AF(af1, rb + 16384 + 4096 + aB0);
    CLUSTER(af0, bf1, 0);

    // P3 (ks1,mq1): stage kt+2 -> rb; prefetch next tile from nb; MFMA af1/bf1
    WAIT_LGKM0();
    __builtin_amdgcn_s_barrier();                    // #1: all rb reads done
    {
      const int st2 = kt + 2 < 64 ? kt + 2 : 63;     // clamped tail source
      STAGE(gA0, 0,     st2, 0, rb);
      STAGE(gA0, 0,     st2, 1, rb);
      STAGE(gB0, 32768, st2, 0, rb);
      STAGE(gB0, 32768, st2, 1, rb);
    }
    asm volatile("s_waitcnt vmcnt(8)" ::: "memory"); // own kt+1 loads retired
    __builtin_amdgcn_s_barrier();                    // #2: all kt+1 landed
    LOAD_AF(af0, nb + aB0);                          // next tile ks0 mq0
    LOAD_BF(bf0, nb + bB);                           // next tile ks0
    CLUSTER(af1, bf1, 1);
  }
  asm volatile("s_waitcnt vmcnt(0) lgkmcnt(0)" ::: "memory");

  // epilogue: C/D layout col = lane&15, row = (lane>>4)*4 + reg
  const int row0 = tm * 256 + wm * 128 + kq * 4;
  const int col0 = tn * 256 + wn * 64 + r16;
#pragma unroll
  for (int nf = 0; nf < 4; ++nf) {
    const int col = col0 + nf * 16;
    const float bv = bias[col];
#pragma unroll
    for (int mf = 0; mf < 8; ++mf) {
      const int row = row0 + mf * 16;
#pragma unroll
      for (int i = 0; i < 4; ++i)
        C[(size_t)(row + i) * GN + col] = acc[mf][nf][i] + bv;
    }
  }
}

// ---------------------------------------------------------------------------
extern "C" void kernel_launch(void* const* d_in, const int* in_sizes, int n_in,
                              void* d_out, int out_size, void* d_ws, size_t ws_size,
                              hipStream_t stream) {
  const float* Q  = (const float*)d_in[0];
  const float* K  = (const float*)d_in[1];
  const float* V  = (const float*)d_in[2];
  const float* Wq = (const float*)d_in[3];
  const float* bq = (const float*)d_in[4];
  const float* Wk = (const float*)d_in[5];
  const float* bk = (const float*)d_in[6];
  const float* Wv = (const float*)d_in[7];
  const float* bv = (const float*)d_in[8];
  const float* Wo = (const float*)d_in[9];
  const float* bo = (const float*)d_in[10];
  float* out = (float*)d_out;

  char* wsb = (char*)d_ws;
  __hip_bfloat16* WoT = (__hip_bfloat16*)wsb;
  __hip_bfloat16* Oc  = (__hip_bfloat16*)(wsb + (size_t)GN * GK * 2);
  __hip_bfloat16* WqT = (__hip_bfloat16*)(wsb + (size_t)GN * GK * 2 + (size_t)GM * GN * 2);
  __hip_bfloat16* WkT = WqT + (size_t)H_SZ * C_SZ * DK;
  __hip_bfloat16* WvT = WkT + (size_t)H_SZ * C_SZ * DK;

  w3_transpose_kernel<<<dim3(2, 2, 96), 256, 0, stream>>>(Wq, Wk, Wv, WqT, WkT, WvT);
  wo_transpose_kernel<<<dim3(64, 64), 256, 0, stream>>>(Wo, WoT);
  attn_kernel<<<dim3(H_SZ, B_SZ), 256, 0, stream>>>(Q, K, V, WqT, bq, WkT, bk, WvT, bv, Oc);
  out_gemm_kernel<<<dim3(13 * 16), 512, 0, stream>>>(Oc, WoT, bo, out);
}

// Round 6
// 216.682 us; speedup vs baseline: 1.0658x; 1.0658x over previous
//
#include <hip/hip_runtime.h>
#include <hip/hip_bf16.h>

// Problem constants
#define B_SZ   64
#define L_SZ   52
#define DMODEL 4096
#define H_SZ   32
#define C_SZ   128   // NEW_C = DMODEL/H
#define DK     128   // D_K == D_V

// Output GEMM dims: (B*L) x DMODEL = 3328 x 4096, K = 4096
#define GM 3328
#define GN 4096
#define GK 4096

typedef __bf16 bf16x8 __attribute__((ext_vector_type(8)));
typedef float  f32x4  __attribute__((ext_vector_type(4)));

__device__ __forceinline__ void gload_lds16(const void* g, void* l) {
  __builtin_amdgcn_global_load_lds(
      (__attribute__((address_space(1))) void*)(void*)g,
      (__attribute__((address_space(3))) void*)l, 16, 0, 0);
}

// ---------------------------------------------------------------------------
// Kernel 1a: Wo (4096x4096 fp32 [m][n]) -> WoT (4096x4096 bf16 [n][m])
// ---------------------------------------------------------------------------
__global__ __launch_bounds__(256) void wo_transpose_kernel(
    const float* __restrict__ Wo, __hip_bfloat16* __restrict__ WoT) {
  __shared__ float tile[64][65];
  const int nt = blockIdx.x, mt = blockIdx.y;
  const int t = threadIdx.x;
  const int r  = t >> 4;
  const int c4 = (t & 15) << 2;
#pragma unroll
  for (int p = 0; p < 4; ++p) {
    const int rr = r + p * 16;
    const float4 v = *(const float4*)(Wo + (size_t)(mt * 64 + rr) * 4096 + nt * 64 + c4);
    tile[rr][c4 + 0] = v.x; tile[rr][c4 + 1] = v.y;
    tile[rr][c4 + 2] = v.z; tile[rr][c4 + 3] = v.w;
  }
  __syncthreads();
#pragma unroll
  for (int p = 0; p < 4; ++p) {
    const int rr = r + p * 16;
    union { __hip_bfloat16 h[4]; ushort4 u; } o4;
#pragma unroll
    for (int e = 0; e < 4; ++e) o4.h[e] = __float2bfloat16(tile[c4 + e][rr]);
    *(ushort4*)(WoT + (size_t)(nt * 64 + rr) * 4096 + mt * 64 + c4) = o4.u;
  }
}

// ---------------------------------------------------------------------------
// Kernel 1b: Wq/Wk/Wv [h][c][k] fp32 -> [h][k][c] bf16   (batched 128x128 T)
// ---------------------------------------------------------------------------
__global__ __launch_bounds__(256) void w3_transpose_kernel(
    const float* __restrict__ Wq, const float* __restrict__ Wk,
    const float* __restrict__ Wv, __hip_bfloat16* __restrict__ WqT,
    __hip_bfloat16* __restrict__ WkT, __hip_bfloat16* __restrict__ WvT) {
  __shared__ float tile[64][65];
  const int bz = blockIdx.z;
  const float* in = (bz < 32 ? Wq : (bz < 64 ? Wk : Wv)) + (size_t)(bz & 31) * 16384;
  __hip_bfloat16* out = (bz < 32 ? WqT : (bz < 64 ? WkT : WvT)) + (size_t)(bz & 31) * 16384;
  const int nt = blockIdx.x, mt = blockIdx.y;  // 0..1
  const int t = threadIdx.x;
  const int r  = t >> 4;
  const int c4 = (t & 15) << 2;
#pragma unroll
  for (int p = 0; p < 4; ++p) {
    const int rr = r + p * 16;
    const float4 v = *(const float4*)(in + (size_t)(mt * 64 + rr) * 128 + nt * 64 + c4);
    tile[rr][c4 + 0] = v.x; tile[rr][c4 + 1] = v.y;
    tile[rr][c4 + 2] = v.z; tile[rr][c4 + 3] = v.w;
  }
  __syncthreads();
#pragma unroll
  for (int p = 0; p < 4; ++p) {
    const int rr = r + p * 16;
    union { __hip_bfloat16 h[4]; ushort4 u; } o4;
#pragma unroll
    for (int e = 0; e < 4; ++e) o4.h[e] = __float2bfloat16(tile[c4 + e][rr]);
    *(ushort4*)(out + (size_t)(nt * 64 + rr) * 128 + mt * 64 + c4) = o4.u;
  }
}

// ---------------------------------------------------------------------------
// Kernel 2: per-(b,h) MFMA attention. 256 threads = 4 waves. (unchanged)
// ---------------------------------------------------------------------------
template <bool TRANSPOSED>
__device__ __forceinline__ void wave_proj(
    const __hip_bfloat16* __restrict__ xs, const __hip_bfloat16* __restrict__ WT,
    const float* __restrict__ bias, __hip_bfloat16* __restrict__ out,
    int n0, int r16, int kq) {
  f32x4 acc[4][2] = {};
  bf16x8 bfrag[2][4];
#pragma unroll
  for (int nt = 0; nt < 2; ++nt)
#pragma unroll
    for (int kk = 0; kk < 4; ++kk)
      bfrag[nt][kk] = *(const bf16x8*)(WT + (n0 + nt * 16 + r16) * 128 + kk * 32 + kq * 8);
#pragma unroll
  for (int kk = 0; kk < 4; ++kk) {
    bf16x8 a[4];
#pragma unroll
    for (int mt = 0; mt < 4; ++mt)
      a[mt] = *(const bf16x8*)(xs + (mt * 16 + r16) * 136 + kk * 32 + kq * 8);
#pragma unroll
    for (int mt = 0; mt < 4; ++mt)
#pragma unroll
      for (int nt = 0; nt < 2; ++nt)
        acc[mt][nt] = __builtin_amdgcn_mfma_f32_16x16x32_bf16(a[mt], bfrag[nt][kk], acc[mt][nt], 0, 0, 0);
  }
#pragma unroll
  for (int nt = 0; nt < 2; ++nt) {
    const int col = n0 + nt * 16 + r16;
    const float bv = bias[col];
#pragma unroll
    for (int mt = 0; mt < 4; ++mt) {
      const int m0 = mt * 16 + kq * 4;
      if (!TRANSPOSED) {
#pragma unroll
        for (int i = 0; i < 4; ++i)
          out[(m0 + i) * 136 + col] = __float2bfloat16(acc[mt][nt][i] + bv);
      } else {
        union { __hip_bfloat16 h[4]; ushort4 u; } o4;
        if (m0 < 52) {
#pragma unroll
          for (int i = 0; i < 4; ++i) o4.h[i] = __float2bfloat16(acc[mt][nt][i] + bv);
        } else {
          o4.u = make_ushort4(0, 0, 0, 0);   // pad keys: v rows 52..63 = 0
        }
        *(ushort4*)(out + col * 72 + m0) = o4.u;
      }
    }
  }
}

__global__ __launch_bounds__(256, 2) void attn_kernel(
    const float* __restrict__ Qin, const float* __restrict__ Kin,
    const float* __restrict__ Vin,
    const __hip_bfloat16* __restrict__ WqT, const float* __restrict__ bq,
    const __hip_bfloat16* __restrict__ WkT, const float* __restrict__ bk,
    const __hip_bfloat16* __restrict__ WvT, const float* __restrict__ bv,
    __hip_bfloat16* __restrict__ Oc) {
  __shared__ __align__(16) char lds[70656];
  __hip_bfloat16* xs0  = (__hip_bfloat16*)(lds);
  __hip_bfloat16* xs1  = (__hip_bfloat16*)(lds + 17408);
  __hip_bfloat16* xs2  = (__hip_bfloat16*)(lds + 34816);
  __hip_bfloat16* vT   = (__hip_bfloat16*)(lds + 52224);
  __hip_bfloat16* q_sh = (__hip_bfloat16*)(lds + 34816);
  __hip_bfloat16* k_sh = (__hip_bfloat16*)(lds);
  float*          s_sh = (float*)(lds + 17408);
  __hip_bfloat16* p_sh = (__hip_bfloat16*)(lds + 34816);

  const int h = blockIdx.x, bb = blockIdx.y;
  const int t = threadIdx.x;
  const int w = t >> 6, lane = t & 63;
  const int r16 = lane & 15, kq = lane >> 4;
  const size_t xoff = (size_t)bb * (L_SZ * DMODEL) + (size_t)h * (L_SZ * C_SZ);

  {
    const float* xp[3] = {Qin + xoff, Kin + xoff, Vin + xoff};
    __hip_bfloat16* xd[3] = {xs0, xs1, xs2};
#pragma unroll
    for (int tz = 0; tz < 3; ++tz) {
      const float* X = xp[tz];
      __hip_bfloat16* xs = xd[tz];
      for (int idx = t; idx < 52 * 32; idx += 256) {
        const int row = idx >> 5, c4 = (idx & 31) << 2;
        const float4 v = *(const float4*)(X + row * 128 + c4);
        union { __hip_bfloat16 h[4]; ushort4 u; } o4;
        o4.h[0] = __float2bfloat16(v.x); o4.h[1] = __float2bfloat16(v.y);
        o4.h[2] = __float2bfloat16(v.z); o4.h[3] = __float2bfloat16(v.w);
        *(ushort4*)(xs + row * 136 + c4) = o4.u;
      }
      if (t < 12 * 17) {
        const int row = 52 + t / 17, c8 = (t % 17) * 8;
        *(uint4*)(xs + row * 136 + c8) = make_uint4(0, 0, 0, 0);
      }
    }
  }
  __syncthreads();

  wave_proj<true>(xs2, WvT + (size_t)h * 16384, bv + h * 128, vT, w * 32, r16, kq);
  __syncthreads();
  wave_proj<false>(xs0, WqT + (size_t)h * 16384, bq + h * 128, q_sh, w * 32, r16, kq);
  __syncthreads();
  wave_proj<false>(xs1, WkT + (size_t)h * 16384, bk + h * 128, k_sh, w * 32, r16, kq);
  __syncthreads();

  {
    const int n0 = w * 16;
    f32x4 sacc[4] = {};
#pragma unroll
    for (int kk = 0; kk < 4; ++kk) {
      const bf16x8 bf_ = *(const bf16x8*)(k_sh + (n0 + r16) * 136 + kk * 32 + kq * 8);
#pragma unroll
      for (int mt = 0; mt < 4; ++mt) {
        const bf16x8 a = *(const bf16x8*)(q_sh + (mt * 16 + r16) * 136 + kk * 32 + kq * 8);
        sacc[mt] = __builtin_amdgcn_mfma_f32_16x16x32_bf16(a, bf_, sacc[mt], 0, 0, 0);
      }
    }
    const float scale = 0.08838834764831845f;  // 1/sqrt(128)
#pragma unroll
    for (int mt = 0; mt < 4; ++mt)
#pragma unroll
      for (int i = 0; i < 4; ++i)
        s_sh[(mt * 16 + kq * 4 + i) * 68 + n0 + r16] = sacc[mt][i] * scale;
  }
  __syncthreads();

  {
    const int r = t >> 2, qd = t & 3;
    if (r < 52) {
      float v[16];
      float mx = -3e38f;
#pragma unroll
      for (int j4 = 0; j4 < 4; ++j4) {
        const f32x4 s4 = *(const f32x4*)(s_sh + r * 68 + qd * 16 + j4 * 4);
#pragma unroll
        for (int e = 0; e < 4; ++e) {
          const int col = qd * 16 + j4 * 4 + e;
          const float val = (col <= r) ? s4[e] : -3e38f;
          v[j4 * 4 + e] = val;
          mx = fmaxf(mx, val);
        }
      }
      mx = fmaxf(mx, __shfl_xor(mx, 1));
      mx = fmaxf(mx, __shfl_xor(mx, 2));
      float ex[16];
      float sum = 0.f;
#pragma unroll
      for (int j = 0; j < 16; ++j) {
        const int col = qd * 16 + j;
        const float e = (col <= r) ? __expf(v[j] - mx) : 0.f;
        ex[j] = e; sum += e;
      }
      sum += __shfl_xor(sum, 1);
      sum += __shfl_xor(sum, 2);
      const float inv = 1.0f / sum;
      union { __hip_bfloat16 h[8]; uint4 q; } p0, p1;
#pragma unroll
      for (int j = 0; j < 8; ++j) {
        p0.h[j] = __float2bfloat16(ex[j] * inv);
        p1.h[j] = __float2bfloat16(ex[8 + j] * inv);
      }
      *(uint4*)(p_sh + r * 72 + qd * 16)     = p0.q;
      *(uint4*)(p_sh + r * 72 + qd * 16 + 8) = p1.q;
    } else {
      *(uint4*)(p_sh + r * 72 + qd * 16)     = make_uint4(0, 0, 0, 0);
      *(uint4*)(p_sh + r * 72 + qd * 16 + 8) = make_uint4(0, 0, 0, 0);
    }
  }
  __syncthreads();

  {
    const int n0 = w * 32;
    f32x4 oacc[4][2] = {};
#pragma unroll
    for (int kk = 0; kk < 2; ++kk) {
      bf16x8 bfr[2];
#pragma unroll
      for (int nt = 0; nt < 2; ++nt)
        bfr[nt] = *(const bf16x8*)(vT + (n0 + nt * 16 + r16) * 72 + kk * 32 + kq * 8);
#pragma unroll
      for (int mt = 0; mt < 4; ++mt) {
        const bf16x8 a = *(const bf16x8*)(p_sh + (mt * 16 + r16) * 72 + kk * 32 + kq * 8);
#pragma unroll
        for (int nt = 0; nt < 2; ++nt)
          oacc[mt][nt] = __builtin_amdgcn_mfma_f32_16x16x32_bf16(a, bfr[nt], oacc[mt][nt], 0, 0, 0);
      }
    }
    const size_t obase = (size_t)bb * 52 * 4096 + (size_t)h * 128;
#pragma unroll
    for (int nt = 0; nt < 2; ++nt) {
      const int col = n0 + nt * 16 + r16;
#pragma unroll
      for (int mt = 0; mt < 4; ++mt) {
        const int row0 = mt * 16 + kq * 4;
#pragma unroll
        for (int i = 0; i < 4; ++i) {
          const int row = row0 + i;
          if (row < 52)
            Oc[obase + (size_t)row * 4096 + col] = __float2bfloat16(oacc[mt][nt][i]);
        }
      }
    }
  }
}

// ---------------------------------------------------------------------------
// Kernel 3: C = Oc @ WoT^T + bo — faithful m201-style 4-phase/K-tile schedule.
// 256x256 tile, BK=64, 512 thr / 8 waves (2Mx4N), 2 LDS bufs of 64 KB.
// Buf: [A-ks0 16K][A-ks1 16K][B-ks0 16K][B-ks1 16K]; region = 16KB = 2 gloads.
// Last-read phase in tile T: B-ks0@p0, A-ks0@p1, B-ks1@p2, A-ks1@p3.
// Stage slots: p0 -> A-ks1(T+1) [other buf]; p1 -> B-ks0(T+2); p2 -> A-ks0(T+2);
// p3 -> B-ks1(T+2) [own buf, each after its last-read phase's closing barrier].
// ONE vmcnt(6) per K-tile (end of p3): leaves exactly the 3 newest stage slots
// (6 loads) in flight => all of tile T+1's regions landed; waited-on load is
// >=3 phases (~1800 cyc) old. Never vmcnt(0) in the loop.
// Phase body: {ds_reads, 1-region stage, s_barrier, lgkmcnt(0)+sched_barrier,
// setprio(1), 16 MFMA, setprio(0), [p3: vmcnt(6)], s_barrier}.
// Swizzle (proven 0-conflict): LDS[row][slot] = G[row][slot ^ ((row>>1)&3)].
// ---------------------------------------------------------------------------
#define STAGE(GBASE, REGOFF, KT, KS, WB) do {                                  \
    const __hip_bfloat16* s_ = (GBASE) + (size_t)(KT) * 64 + (KS) * 32;        \
    char* d_ = (WB) + (REGOFF) + ((KS) ? 16384 : 0) + t * 16;                  \
    gload_lds16(s_, d_);                                                       \
    gload_lds16(s_ + (size_t)128 * GK, d_ + 8192);                             \
  } while (0)

#define MFMA16(MQ, BF)                                                         \
  __builtin_amdgcn_sched_barrier(0);                                           \
  __builtin_amdgcn_s_setprio(1);                                               \
  _Pragma("unroll")                                                            \
  for (int mf = 0; mf < 4; ++mf)                                               \
    _Pragma("unroll")                                                          \
    for (int nf = 0; nf < 4; ++nf)                                             \
      acc[(MQ) * 4 + mf][nf] = __builtin_amdgcn_mfma_f32_16x16x32_bf16(        \
          af[mf], BF[nf], acc[(MQ) * 4 + mf][nf], 0, 0, 0);                    \
  __builtin_amdgcn_s_setprio(0)

#define READ_AF(KS, MQ)                                                        \
  _Pragma("unroll")                                                            \
  for (int mf = 0; mf < 4; ++mf)                                               \
    af[mf] = *(const bf16x8*)(rb + (KS) * 16384 + (MQ) * 4096 + aB0 + mf * 1024)

#define READ_BF(BF, KS)                                                        \
  _Pragma("unroll")                                                            \
  for (int nf = 0; nf < 4; ++nf)                                               \
    BF[nf] = *(const bf16x8*)(rb + 32768 + (KS) * 16384 + bB0 + nf * 1024)

__global__ __launch_bounds__(512, 2) void out_gemm_kernel(
    const __hip_bfloat16* __restrict__ A, const __hip_bfloat16* __restrict__ Bt,
    const float* __restrict__ bias, float* __restrict__ C) {
  __shared__ __align__(16) char lds[131072];   // 2 bufs x 64 KB

  int bid = blockIdx.x;
  bid = (bid & 7) * 26 + (bid >> 3);     // XCD swizzle, 208 % 8 == 0 (bijective)
  const int tm = bid >> 4;               // 0..12
  const int tn = bid & 15;               // 0..15

  const int t = threadIdx.x;
  const int w = t >> 6, lane = t & 63;
  const int wm = w >> 2, wn = w & 3;     // 2M x 4N waves; wave tile 128x64
  const int r16 = lane & 15, kq = lane >> 4;

  // staging: thread t -> LDS row t>>2 (+128 for 2nd gload), slot t&3;
  // global k-slot = (t&3) ^ ((row>>1)&3)   [swizzle involution]
  const int srow = t >> 2;
  const int sgslot = (t & 3) ^ ((srow >> 1) & 3);
  const __hip_bfloat16* gA0 = A  + (size_t)(tm * 256 + srow) * GK + sgslot * 8;
  const __hip_bfloat16* gB0 = Bt + (size_t)(tn * 256 + srow) * GK + sgslot * 8;

  // read-side bases (byte): row*64 + (kq ^ ((r16>>1)&3))*16
  const int slotr = kq ^ ((r16 >> 1) & 3);
  const int aB0 = (wm * 128 + r16) * 64 + slotr * 16;
  const int bB0 = (wn * 64 + r16) * 64 + slotr * 16;

  f32x4 acc[8][4] = {};
  bf16x8 bf0[4], bf1[4];

  // prologue: T0 all 4 regions -> buf0; T1 {B-ks0, A-ks0, B-ks1} -> buf1
  // (A-ks1(T1) is staged by T0.p0's steady-state slot)
  STAGE(gA0, 0,     0, 0, lds);
  STAGE(gA0, 0,     0, 1, lds);
  STAGE(gB0, 32768, 0, 0, lds);
  STAGE(gB0, 32768, 0, 1, lds);
  STAGE(gB0, 32768, 1, 0, lds + 65536);
  STAGE(gA0, 0,     1, 0, lds + 65536);
  STAGE(gB0, 32768, 1, 1, lds + 65536);
  asm volatile("s_waitcnt vmcnt(6)" ::: "memory");   // T0's 8 loads landed
  __builtin_amdgcn_s_barrier();

#pragma unroll 1
  for (int kt = 0; kt < 64; ++kt) {
    char* rb = lds + ((kt & 1) << 16);         // read buffer (tile kt)
    char* ob = lds + (((kt + 1) & 1) << 16);   // other buffer (tile kt+1)
    const int s1 = kt + 1 < 64 ? kt + 1 : 63;  // clamped stage sources
    const int s2 = kt + 2 < 64 ? kt + 2 : 63;

    // p0 (ks0,mq0): + B(ks0); stage A-ks1(T+1) -> ob
    {
      bf16x8 af[4];
      READ_AF(0, 0);
      READ_BF(bf0, 0);
      STAGE(gA0, 0, s1, 1, ob);
      __builtin_amdgcn_s_barrier();
      asm volatile("s_waitcnt lgkmcnt(0)" ::: "memory");
      MFMA16(0, bf0);
      __builtin_amdgcn_s_barrier();
    }
    // p1 (ks0,mq1): stage B-ks0(T+2) -> rb (B-ks0 last read was p0)
    {
      bf16x8 af[4];
      READ_AF(0, 1);
      STAGE(gB0, 32768, s2, 0, rb);
      __builtin_amdgcn_s_barrier();
      asm volatile("s_waitcnt lgkmcnt(0)" ::: "memory");
      MFMA16(1, bf0);
      __builtin_amdgcn_s_barrier();
    }
    // p2 (ks1,mq0): + B(ks1); stage A-ks0(T+2) -> rb (A-ks0 last read was p1)
    {
      bf16x8 af[4];
      READ_AF(1, 0);
      READ_BF(bf1, 1);
      STAGE(gA0, 0, s2, 0, rb);
      __builtin_amdgcn_s_barrier();
      asm volatile("s_waitcnt lgkmcnt(0)" ::: "memory");
      MFMA16(0, bf1);
      __builtin_amdgcn_s_barrier();
    }
    // p3 (ks1,mq1): stage B-ks1(T+2) -> rb (B-ks1 last read was p2); vmcnt(6)
    {
      bf16x8 af[4];
      READ_AF(1, 1);
      STAGE(gB0, 32768, s2, 1, rb);
      __builtin_amdgcn_s_barrier();
      asm volatile("s_waitcnt lgkmcnt(0)" ::: "memory");
      MFMA16(1, bf1);
      asm volatile("s_waitcnt vmcnt(6)" ::: "memory");  // T+1 fully landed
      __builtin_amdgcn_s_barrier();
    }
  }
  asm volatile("s_waitcnt vmcnt(0) lgkmcnt(0)" ::: "memory");

  // epilogue: C/D layout col = lane&15, row = (lane>>4)*4 + reg
  const int row0 = tm * 256 + wm * 128 + kq * 4;
  const int col0 = tn * 256 + wn * 64 + r16;
#pragma unroll
  for (int nf = 0; nf < 4; ++nf) {
    const int col = col0 + nf * 16;
    const float bv = bias[col];
#pragma unroll
    for (int mf = 0; mf < 8; ++mf) {
      const int row = row0 + mf * 16;
#pragma unroll
      for (int i = 0; i < 4; ++i)
        C[(size_t)(row + i) * GN + col] = acc[mf][nf][i] + bv;
    }
  }
}

// ---------------------------------------------------------------------------
extern "C" void kernel_launch(void* const* d_in, const int* in_sizes, int n_in,
                              void* d_out, int out_size, void* d_ws, size_t ws_size,
                              hipStream_t stream) {
  const float* Q  = (const float*)d_in[0];
  const float* K  = (const float*)d_in[1];
  const float* V  = (const float*)d_in[2];
  const float* Wq = (const float*)d_in[3];
  const float* bq = (const float*)d_in[4];
  const float* Wk = (const float*)d_in[5];
  const float* bk = (const float*)d_in[6];
  const float* Wv = (const float*)d_in[7];
  const float* bv = (const float*)d_in[8];
  const float* Wo = (const float*)d_in[9];
  const float* bo = (const float*)d_in[10];
  float* out = (float*)d_out;

  char* wsb = (char*)d_ws;
  __hip_bfloat16* WoT = (__hip_bfloat16*)wsb;
  __hip_bfloat16* Oc  = (__hip_bfloat16*)(wsb + (size_t)GN * GK * 2);
  __hip_bfloat16* WqT = (__hip_bfloat16*)(wsb + (size_t)GN * GK * 2 + (size_t)GM * GN * 2);
  __hip_bfloat16* WkT = WqT + (size_t)H_SZ * C_SZ * DK;
  __hip_bfloat16* WvT = WkT + (size_t)H_SZ * C_SZ * DK;

  w3_transpose_kernel<<<dim3(2, 2, 96), 256, 0, stream>>>(Wq, Wk, Wv, WqT, WkT, WvT);
  wo_transpose_kernel<<<dim3(64, 64), 256, 0, stream>>>(Wo, WoT);
  attn_kernel<<<dim3(H_SZ, B_SZ), 256, 0, stream>>>(Q, K, V, WqT, bq, WkT, bk, WvT, bv, Oc);
  out_gemm_kernel<<<dim3(13 * 16), 512, 0, stream>>>(Oc, WoT, bo, out);
}